// Round 1
// baseline (5820.837 us; speedup 1.0000x reference)
//
#include <hip/hip_runtime.h>
#include <cstdint>

#define PP 4
#define TT 4
#define NN 16384
#define DD 256
#define HH 4
#define EE 131072
#define BB 32
#define KK 10
#define OUTD 4
#define NPG 512
#define DTOT 1280   /* (P+1)*D */
#define FIN 12801
#define HID 6400

// ---------------- GEMM: C[16384,1024] = A(lda=DTOT) @ B[256,1024] ----------------
__global__ __launch_bounds__(256) void gemm_xp(const float* __restrict__ A,
                                               const float* __restrict__ Bm,
                                               float* __restrict__ C) {
  __shared__ float As[16][132];
  __shared__ float Bs[16][132];
  const int tid = threadIdx.x;
  const int bm = blockIdx.x;   // 0..127
  const int bn = blockIdx.y;   // 0..7
  const int tx = tid & 15, ty = tid >> 4;
  const int m0 = ty * 8, n0 = tx * 8;
  float acc[8][8] = {};
  const int am  = tid >> 1;
  const int akq = (tid & 1) * 8;
  const int arow = bm * 128 + am;
  const int bk  = tid >> 4;        // 0..15
  const int bn4 = (tid & 15) * 8;  // 0..120

  for (int kt = 0; kt < 256; kt += 16) {
    float4 a0 = *(const float4*)(A + (size_t)arow * DTOT + kt + akq);
    float4 a1 = *(const float4*)(A + (size_t)arow * DTOT + kt + akq + 4);
    float4 b0 = *(const float4*)(Bm + (size_t)(kt + bk) * 1024 + bn * 128 + bn4);
    float4 b1 = *(const float4*)(Bm + (size_t)(kt + bk) * 1024 + bn * 128 + bn4 + 4);
    __syncthreads();
    As[akq + 0][am] = a0.x; As[akq + 1][am] = a0.y;
    As[akq + 2][am] = a0.z; As[akq + 3][am] = a0.w;
    As[akq + 4][am] = a1.x; As[akq + 5][am] = a1.y;
    As[akq + 6][am] = a1.z; As[akq + 7][am] = a1.w;
    *(float4*)&Bs[bk][bn4]     = b0;
    *(float4*)&Bs[bk][bn4 + 4] = b1;
    __syncthreads();
#pragma unroll
    for (int k = 0; k < 16; ++k) {
      float4 x0 = *(const float4*)&As[k][m0];
      float4 x1 = *(const float4*)&As[k][m0 + 4];
      float4 y0 = *(const float4*)&Bs[k][n0];
      float4 y1 = *(const float4*)&Bs[k][n0 + 4];
      float av[8] = {x0.x, x0.y, x0.z, x0.w, x1.x, x1.y, x1.z, x1.w};
      float bv[8] = {y0.x, y0.y, y0.z, y0.w, y1.x, y1.y, y1.z, y1.w};
#pragma unroll
      for (int i = 0; i < 8; ++i)
#pragma unroll
        for (int j = 0; j < 8; ++j) acc[i][j] += av[i] * bv[j];
    }
  }
  const int crow0 = bm * 128 + m0;
  const int ccol0 = bn * 128 + n0;
#pragma unroll
  for (int i = 0; i < 8; ++i) {
    float4 c0 = make_float4(acc[i][0], acc[i][1], acc[i][2], acc[i][3]);
    float4 c1 = make_float4(acc[i][4], acc[i][5], acc[i][6], acc[i][7]);
    *(float4*)(C + (size_t)(crow0 + i) * 1024 + ccol0)     = c0;
    *(float4*)(C + (size_t)(crow0 + i) * 1024 + ccol0 + 4) = c1;
  }
}

// ---------------- per-node attention scores ----------------
__global__ __launch_bounds__(256) void attn_scores(const float* __restrict__ xp,
                                                   const float* __restrict__ av_s,
                                                   const float* __restrict__ av_d,
                                                   float* __restrict__ als,
                                                   float* __restrict__ ald) {
  int i = blockIdx.x;
  int h = threadIdx.x >> 6;
  int lane = threadIdx.x & 63;
  const float* row = xp + ((size_t)i * HH + h) * DD;
  const float* sa = av_s + h * DD;
  const float* da = av_d + h * DD;
  float ss = 0.f, sd = 0.f;
  for (int d = lane; d < DD; d += 64) {
    float v = row[d];
    ss += v * sa[d];
    sd += v * da[d];
  }
  for (int off = 32; off > 0; off >>= 1) {
    ss += __shfl_down(ss, off, 64);
    sd += __shfl_down(sd, off, 64);
  }
  if (lane == 0) { als[i * HH + h] = ss; ald[i * HH + h] = sd; }
}

// ---------------- self-loop init of num/den ----------------
__global__ __launch_bounds__(256) void selfloop_init(const float* __restrict__ xp,
                                                     const float* __restrict__ als,
                                                     const float* __restrict__ ald,
                                                     float* __restrict__ num,
                                                     float* __restrict__ den) {
  int i = blockIdx.x, d = threadIdx.x;
#pragma unroll
  for (int h = 0; h < HH; ++h) {
    float l = als[i * HH + h] + ald[i * HH + h];
    l = l > 0.f ? l : 0.2f * l;
    float w = expf(l);
    size_t o = ((size_t)i * HH + h) * DD + d;
    num[o] = w * xp[o];
    if (d == 0) den[i * HH + h] = w;
  }
}

// ---------------- edge accumulation (atomics) ----------------
__global__ __launch_bounds__(256) void edge_kernel(const int* __restrict__ ei,
                                                   const int* __restrict__ ea,
                                                   const float* __restrict__ als,
                                                   const float* __restrict__ ald,
                                                   const float* __restrict__ xp,
                                                   float* __restrict__ num,
                                                   float* __restrict__ den,
                                                   int t) {
  int e = blockIdx.x;
  int src = ei[e], dst = ei[EE + e];
  if (src == dst || ea[e] != t) return;
  int tid = threadIdx.x;
  if (tid < HH) {
    float l = als[src * HH + tid] + ald[dst * HH + tid];
    l = l > 0.f ? l : 0.2f * l;
    atomicAdd(&den[dst * HH + tid], expf(l));
  }
#pragma unroll
  for (int h = 0; h < HH; ++h) {
    float l = als[src * HH + h] + ald[dst * HH + h];
    l = l > 0.f ? l : 0.2f * l;
    float w = expf(l);
    atomicAdd(&num[((size_t)dst * HH + h) * DD + tid],
              w * xp[((size_t)src * HH + h) * DD + tid]);
  }
}

// ---------------- head mean + bias + leaky + accumulate over t ----------------
__global__ __launch_bounds__(256) void head_mean_acc(const float* __restrict__ num,
                                                     const float* __restrict__ den,
                                                     const float* __restrict__ bias,
                                                     float* __restrict__ acc,
                                                     int first) {
  int i = blockIdx.x, d = threadIdx.x;
  float s = 0.f;
#pragma unroll
  for (int h = 0; h < HH; ++h)
    s += num[((size_t)i * HH + h) * DD + d] / den[i * HH + h];
  float val = s * (1.f / HH) + bias[d];
  val = val > 0.f ? val : 0.01f * val;
  if (first) acc[(size_t)i * DD + d] = val;
  else       acc[(size_t)i * DD + d] += val;
}

__global__ void x_update(const float* __restrict__ acc, float* __restrict__ xc, int p) {
  int i = blockIdx.x, d = threadIdx.x;
  xc[(size_t)i * DTOT + (p + 1) * DD + d] = acc[(size_t)i * DD + d] * (1.f / TT);
}

__global__ void x_copy(const float* __restrict__ x, float* __restrict__ xc) {
  int i = blockIdx.x, d = threadIdx.x;
  xc[(size_t)i * DTOT + d] = x[(size_t)i * DD + d];
}

// ---------------- sort pool: per-graph top-K by last channel ----------------
__global__ __launch_bounds__(256) void sort_pool(const float* __restrict__ xc,
                                                 int* __restrict__ topk) {
  __shared__ float vals[NPG];
  __shared__ float rv[256];
  __shared__ int   ri[256];
  int b = blockIdx.x, tid = threadIdx.x;
  for (int i = tid; i < NPG; i += 256)
    vals[i] = xc[(size_t)(b * NPG + i) * DTOT + (DTOT - 1)];
  __syncthreads();
  for (int k = 0; k < KK; ++k) {
    float bv = -3.4e38f; int bi = NPG;
    for (int i = tid; i < NPG; i += 256) {
      float v = vals[i];
      if (v > bv || (v == bv && i < bi)) { bv = v; bi = i; }
    }
    rv[tid] = bv; ri[tid] = bi;
    __syncthreads();
    for (int s = 128; s > 0; s >>= 1) {
      if (tid < s) {
        float v2 = rv[tid + s]; int i2 = ri[tid + s];
        if (v2 > rv[tid] || (v2 == rv[tid] && i2 < ri[tid])) { rv[tid] = v2; ri[tid] = i2; }
      }
      __syncthreads();
    }
    if (tid == 0) { topk[b * KK + k] = b * NPG + ri[0]; vals[ri[0]] = -3.4e38f; }
    __syncthreads();
  }
}

__global__ void gather_pool(const float* __restrict__ xc, const int* __restrict__ topk,
                            const float* __restrict__ ptype, float* __restrict__ pooledT) {
  int bk = blockIdx.x;  // B*K
  int b = bk / KK, k = bk % KK;
  int node = topk[bk];
  for (int j = threadIdx.x; j < DTOT; j += 256)
    pooledT[(size_t)(k * DTOT + j) * BB + b] = xc[(size_t)node * DTOT + j];
  if (k == 0 && threadIdx.x == 0)
    pooledT[(size_t)(FIN - 1) * BB + b] = ptype[b];
}

__global__ void zero_f(float* p, int n) {
  int i = blockIdx.x * 256 + threadIdx.x;
  if (i < n) p[i] = 0.f;
}

// ---------------- FC: outRaw[j][b] += sum_f inT[f][b]*W[f][j] ----------------
__global__ __launch_bounds__(256) void fc_accum(const float* __restrict__ inT,
                                                const float* __restrict__ W,
                                                float* __restrict__ outRaw,
                                                int Kdim, int Jdim, int fchunk) {
  int j = blockIdx.x * 256 + threadIdx.x;
  int f0 = blockIdx.y * fchunk;
  int f1 = f0 + fchunk; if (f1 > Kdim) f1 = Kdim;
  float acc[BB];
#pragma unroll
  for (int b = 0; b < BB; ++b) acc[b] = 0.f;
  for (int f = f0; f < f1; ++f) {
    float wv = W[(size_t)f * Jdim + j];
    const float* row = inT + (size_t)f * BB;
#pragma unroll
    for (int b = 0; b < BB; ++b) acc[b] += row[b] * wv;
  }
#pragma unroll
  for (int b = 0; b < BB; ++b) atomicAdd(&outRaw[(size_t)j * BB + b], acc[b]);
}

__global__ void fc_final(float* __restrict__ ioT, const float* __restrict__ bias, int Jdim) {
  int idx = blockIdx.x * 256 + threadIdx.x;
  if (idx >= Jdim * BB) return;
  int j = idx / BB;
  float v = ioT[idx] + bias[j];
  ioT[idx] = v > 0.f ? v : 0.01f * v;
}

__global__ __launch_bounds__(128) void fc3_kernel(const float* __restrict__ h2T,
                                                  const float* __restrict__ w3,
                                                  const float* __restrict__ b3,
                                                  float* __restrict__ out) {
  int tid = threadIdx.x;  // 128 = 32 b * 4 o
  int o = tid & 3, b = tid >> 2;
  float a0 = 0.f, a1 = 0.f, a2 = 0.f, a3 = 0.f;
  for (int f = 0; f < HID; f += 4) {
    a0 += h2T[(size_t)f * BB + b]       * w3[(size_t)f * OUTD + o];
    a1 += h2T[(size_t)(f + 1) * BB + b] * w3[(size_t)(f + 1) * OUTD + o];
    a2 += h2T[(size_t)(f + 2) * BB + b] * w3[(size_t)(f + 2) * OUTD + o];
    a3 += h2T[(size_t)(f + 3) * BB + b] * w3[(size_t)(f + 3) * OUTD + o];
  }
  out[b * OUTD + o] = a0 + a1 + a2 + a3 + b3[o];
}

extern "C" void kernel_launch(void* const* d_in, const int* in_sizes, int n_in,
                              void* d_out, int out_size, void* d_ws, size_t ws_size,
                              hipStream_t stream) {
  const float* x       = (const float*)d_in[0];
  const float* ptype   = (const float*)d_in[1];
  const float* W       = (const float*)d_in[2];
  const float* att_src = (const float*)d_in[3];
  const float* att_dst = (const float*)d_in[4];
  const float* bias_g  = (const float*)d_in[5];
  const float* fc1_w   = (const float*)d_in[6];
  const float* fc1_b   = (const float*)d_in[7];
  const float* fc2_w   = (const float*)d_in[8];
  const float* fc2_b   = (const float*)d_in[9];
  const float* fc3_w   = (const float*)d_in[10];
  const float* fc3_b   = (const float*)d_in[11];
  const int*   ei      = (const int*)d_in[12];
  const int*   ea      = (const int*)d_in[13];
  float* out = (float*)d_out;

  float* ws = (float*)d_ws;
  size_t o = 0;
  float* xc  = ws + o; o += (size_t)NN * DTOT;
  float* xp  = ws + o; o += (size_t)NN * HH * DD;
  float* num = ws + o; o += (size_t)NN * HH * DD;
  float* den = ws + o; o += (size_t)NN * HH;
  float* als = ws + o; o += (size_t)NN * HH;
  float* ald = ws + o; o += (size_t)NN * HH;
  float* acc = ws + o; o += (size_t)NN * DD;
  float* pooledT = ws + o; o += (size_t)FIN * BB;
  float* h1  = ws + o; o += (size_t)HID * BB;
  float* h2  = ws + o; o += (size_t)HID * BB;
  int* topk  = (int*)(ws + o); o += BB * KK;

  x_copy<<<NN, 256, 0, stream>>>(x, xc);

  for (int p = 0; p < PP; ++p) {
    const float* xin = xc + (size_t)p * DD;  // column slice, row stride DTOT
    for (int t = 0; t < TT; ++t) {
      int pt = p * TT + t;
      gemm_xp<<<dim3(128, 8), 256, 0, stream>>>(xin, W + (size_t)pt * DD * HH * DD, xp);
      attn_scores<<<NN, 256, 0, stream>>>(xp, att_src + (size_t)pt * HH * DD,
                                          att_dst + (size_t)pt * HH * DD, als, ald);
      selfloop_init<<<NN, 256, 0, stream>>>(xp, als, ald, num, den);
      edge_kernel<<<EE, 256, 0, stream>>>(ei, ea, als, ald, xp, num, den, t);
      head_mean_acc<<<NN, 256, 0, stream>>>(num, den, bias_g + (size_t)pt * DD, acc,
                                            t == 0 ? 1 : 0);
    }
    x_update<<<NN, 256, 0, stream>>>(acc, xc, p);
  }

  sort_pool<<<BB, 256, 0, stream>>>(xc, topk);
  gather_pool<<<BB * KK, 256, 0, stream>>>(xc, topk, ptype, pooledT);

  zero_f<<<(HID * BB + 255) / 256, 256, 0, stream>>>(h1, HID * BB);
  {
    int nf = 16, chunk = (FIN + nf - 1) / nf;
    fc_accum<<<dim3(HID / 256, nf), 256, 0, stream>>>(pooledT, fc1_w, h1, FIN, HID, chunk);
  }
  fc_final<<<(HID * BB + 255) / 256, 256, 0, stream>>>(h1, fc1_b, HID);

  zero_f<<<(HID * BB + 255) / 256, 256, 0, stream>>>(h2, HID * BB);
  {
    int nf = 8, chunk = (HID + nf - 1) / nf;
    fc_accum<<<dim3(HID / 256, nf), 256, 0, stream>>>(h1, fc2_w, h2, HID, HID, chunk);
  }
  fc_final<<<(HID * BB + 255) / 256, 256, 0, stream>>>(h2, fc2_b, HID);

  fc3_kernel<<<1, 128, 0, stream>>>(h2, fc3_w, fc3_b, out);
}